// Round 10
// baseline (478.279 us; speedup 1.0000x reference)
//
#include <hip/hip_runtime.h>
#include <hip/hip_bf16.h>
#include <math.h>

// Problem constants
#define BB 4
#define VV 8192
#define EE 256
#define HH 8
#define KK 6
#define NP (BB*VV)          // 32768 points total

// ---------------- workspace layout (bytes), total ~86.7 MB ----------------
#define OFF_XV4  0            // float4[NP]            524288
#define OFF_KNN  524288       // int[NP*6]             786432
#define OFF_XWS  1310720      // float[NP]             131072
#define OFF_XWC  1441792      // float[NP]             131072
#define OFF_XB   1572864      // bf16[NP*256]          16777216
#define OFF_WB   18350080     // bf16[1024*256]        524288
#define OFF_QKV  18874368     // bf16[NP*768]          50331648
#define OFF_AO   69206016     // bf16[NP*256]          16777216
#define OFF_SXV  85983232     // float4[NP] sorted     524288
#define OFF_SPM  86507520     // int[NP] perm          131072  -> ends 86638592

typedef float f32x4 __attribute__((ext_vector_type(4)));
typedef __bf16 bf16x8 __attribute__((ext_vector_type(8)));

__device__ __forceinline__ unsigned short f2b(float f) {
  __hip_bfloat16 h = __float2bfloat16(f);
  return *reinterpret_cast<unsigned short*>(&h);
}
__device__ __forceinline__ float b2f(unsigned short u) {
  unsigned v = ((unsigned)u) << 16;
  return __uint_as_float(v);
}

// monotone float -> uint map (total order)
__device__ __forceinline__ unsigned sortable(float f) {
  unsigned u = __float_as_uint(f);
  return u ^ ((unsigned)((int)u >> 31) | 0x80000000u);
}
__device__ __forceinline__ unsigned long long pack_key(float dist, int j) {
  return ((unsigned long long)sortable(dist) << 32) | (unsigned)j;
}
__device__ __forceinline__ float unpack_dist(unsigned long long k) {
  unsigned du = (unsigned)(k >> 32);
  du = (du & 0x80000000u) ? (du ^ 0x80000000u) : ~du;
  return __uint_as_float(du);
}

// key for an empty slot: dist=+INF, idx=0xFFFFFFFF
#define KINF 0xFF800000FFFFFFFFull

#define INSU(key) \
  if (key < k5) { \
    bool b4 = key < k4, b3 = key < k3, b2 = key < k2, b1 = key < k1, b0 = key < k0; \
    k5 = b4 ? k4 : key; \
    k4 = b4 ? (b3 ? k3 : key) : k4; \
    k3 = b3 ? (b2 ? k2 : key) : k3; \
    k2 = b2 ? (b1 ? k1 : key) : k2; \
    k1 = b1 ? (b0 ? k0 : key) : k1; \
    k0 = b0 ? key : k0; \
  }

// ---------------- prep: pack xyz+sq, zero scatter accumulators ----------------
__global__ void prep_kernel(const float* __restrict__ xv, float4* __restrict__ xv4,
                            float* __restrict__ xw_sum, float* __restrict__ xw_cnt) {
  int i = blockIdx.x * blockDim.x + threadIdx.x;
  if (i >= NP) return;
  float x0 = xv[i*3+0], x1 = xv[i*3+1], x2 = xv[i*3+2];
  // exact fp32 op order of the reference: ((x0*x0 + x1*x1) + x2*x2), no FMA contraction
  float sq = __fadd_rn(__fadd_rn(__fmul_rn(x0,x0), __fmul_rn(x1,x1)), __fmul_rn(x2,x2));
  xv4[i] = make_float4(x0, x1, x2, sq);
  xw_sum[i] = 0.f;
  xw_cnt[i] = 0.f;
}

// ---------------- f32 -> bf16 bulk convert (RNE) ----------------
__global__ void cvt_bf16(const float* __restrict__ src, unsigned short* __restrict__ dst, int n4) {
  int i = blockIdx.x * blockDim.x + threadIdx.x;
  if (i >= n4) return;
  float4 v = ((const float4*)src)[i];
  ushort4 o;
  o.x = f2b(v.x); o.y = f2b(v.y); o.z = f2b(v.z); o.w = f2b(v.w);
  ((ushort4*)dst)[i] = o;
}

// ---------------- per-batch bitonic sort by x (u64 keys in LDS) ----------------
// One block per batch, 1024 threads. key = sortable(x)<<32 | local_idx. (r7-proven)
__global__ __launch_bounds__(1024) void sort_kernel(const float4* __restrict__ xv4,
                                                    float4* __restrict__ sxv4,
                                                    int* __restrict__ sperm) {
  __shared__ unsigned long long keys[VV];   // 64 KB
  int tid = threadIdx.x;
  int bb = blockIdx.x * VV;
#pragma unroll
  for (int t = 0; t < 8; ++t) {
    int i = tid + t*1024;
    keys[i] = ((unsigned long long)sortable(xv4[bb + i].x) << 32) | (unsigned)i;
  }
  for (int k = 2; k <= VV; k <<= 1) {
    for (int jj = k >> 1; jj > 0; jj >>= 1) {
      __syncthreads();
#pragma unroll
      for (int t = 0; t < 4; ++t) {
        int c = tid + t*1024;                           // comparator 0..4095
        int i = ((c & ~(jj-1)) << 1) | (c & (jj-1));
        int p = i + jj;
        bool up = ((i & k) == 0);
        unsigned long long a = keys[i], b = keys[p];
        if ((a > b) == up) { keys[i] = b; keys[p] = a; }
      }
    }
  }
  __syncthreads();
#pragma unroll
  for (int t = 0; t < 8; ++t) {
    int r = tid + t*1024;
    int idx = (int)(unsigned)keys[r];    // batch-LOCAL original index
    sxv4[bb + r] = xv4[bb + idx];
    sperm[bb + r] = idx;
  }
}

// ---------------- KNN via sorted-x window scan (chunked, throughput-structured) --
// Block = 256 threads = 4 waves; 64 queries/block (one per lane); wave = one of 4
// interleaved streams {left,right} x {even,odd}, stride 2. Per chunk: 8 INDEPENDENT
// clamped loads batched into registers (8 outstanding, no data-dependent branch
// between them), then 8 process steps. Early-out via wave-uniform __ballot once
// per chunk. Stop rule per lane: dx^2 > d5 + MARGIN (conservative vs <=1e-5 fp32
// rounding of the reference-order distance; sorted => dx^2 monotone => done flag
// monotone). Exact tie-break via packed u64 (sortable dist, batch-local idx).
#define MARGIN 1e-3f

__global__ __launch_bounds__(256) void knn_scan(const float4* __restrict__ sxv4,
                                                const int* __restrict__ sperm,
                                                int* __restrict__ knn_idx) {
  __shared__ unsigned long long sk[64][25];   // 4 sides x 6 keys (+pad)
  int lane = threadIdx.x & 63;
  int side = threadIdx.x >> 6;                // 0:left-odd 1:left-even 2:self+right-even 3:right-odd
  int g = blockIdx.x * 64 + lane;             // global sorted position
  int bb = (g >> 13) << 13;                   // batch base (8192 % 64 == 0)
  int lastp = bb + VV - 1;

  float4 me = sxv4[g];
  float mx = me.x, my = me.y, mz = me.z, sqq = me.w;
  int myidx = sperm[g];                       // batch-LOCAL original index

  unsigned long long k0=KINF,k1=KINF,k2=KINF,k3=KINF,k4=KINF,k5=KINF;
  float d5f = INFINITY, thr = INFINITY;       // thr = d5f + MARGIN

  int step = (side & 2) ? 2 : -2;
  int p = (side == 0) ? g - 1 : (side == 1) ? g - 2 : (side == 2) ? g : g + 1;
  bool done = false;

  for (int guard = 0; guard < VV/8; ++guard) {
    float4 cc[8];
#pragma unroll
    for (int u = 0; u < 8; ++u) {
      int pi = p + u*step;
      int pc = min(max(pi, bb), lastp);
      cc[u] = sxv4[pc];                        // independent, clamped → 8 in flight
    }
#pragma unroll
    for (int u = 0; u < 8; ++u) {
      int pi = p + u*step;
      bool inb = (unsigned)(pi - bb) < (unsigned)VV;
      float4 c = cc[u];
      float dxv = __fsub_rn(mx, c.x);
      float dx2 = __fmul_rn(dxv, dxv);
      // reference fp32 semantics: d = (sq_v + sq_w) - 2*((xx+yy)+zz)
      float dot  = __fadd_rn(__fadd_rn(__fmul_rn(mx,c.x), __fmul_rn(my,c.y)), __fmul_rn(mz,c.z));
      float dist = __fsub_rn(__fadd_rn(sqq, c.w), __fmul_rn(2.0f, dot));
      if (inb && dist <= d5f) {
        int pc = min(max(pi, bb), lastp);
        unsigned long long key = pack_key(dist, sperm[pc]);
        if (key < k5) {
          bool b4 = key < k4, b3 = key < k3, b2 = key < k2, b1 = key < k1, b0 = key < k0;
          k5 = b4 ? k4 : key;
          k4 = b4 ? (b3 ? k3 : key) : k4;
          k3 = b3 ? (b2 ? k2 : key) : k3;
          k2 = b2 ? (b1 ? k1 : key) : k2;
          k1 = b1 ? (b0 ? k0 : key) : k1;
          k0 = b0 ? key : k0;
          d5f = unpack_dist(k5);
          thr = __fadd_rn(d5f, MARGIN);
        }
      }
      done = done || (!inb) || (dx2 > thr);
    }
    p += 8*step;
    if (__ballot(!done) == 0ull) break;        // wave-uniform early-out, 1/chunk
  }

  sk[lane][side*6+0]=k0; sk[lane][side*6+1]=k1; sk[lane][side*6+2]=k2;
  sk[lane][side*6+3]=k3; sk[lane][side*6+4]=k4; sk[lane][side*6+5]=k5;
  __syncthreads();
  if (side == 0) {
#pragma unroll
    for (int s = 6; s < 24; ++s) {
      unsigned long long key = sk[lane][s];
      INSU(key);
    }
    int grow = bb + myidx;    // GLOBAL point id
    knn_idx[grow*6+0] = (int)(unsigned)k0;
    knn_idx[grow*6+1] = (int)(unsigned)k1;
    knn_idx[grow*6+2] = (int)(unsigned)k2;
    knn_idx[grow*6+3] = (int)(unsigned)k3;
    knn_idx[grow*6+4] = (int)(unsigned)k4;
    knn_idx[grow*6+5] = (int)(unsigned)k5;
  }
}

// ---------------- bf16 MFMA GEMM: C[m,n] = sum_k A[m,k]*B[n,k], K=256 ----------------
template<bool OUT_BF16>
__global__ __launch_bounds__(256) void gemm_bf16(const unsigned short* __restrict__ A,
                                                 const unsigned short* __restrict__ Bw,
                                                 void* __restrict__ Cv,
                                                 const float* __restrict__ R,
                                                 int ldc) {
  __shared__ unsigned short ABs[8192];   // A tile [0,4096), B tile [4096,8192) ushort units
  int tid = threadIdx.x;
  int lane = tid & 63;
  int w = tid >> 6;
  int bm = blockIdx.x * 128;
  int bn = blockIdx.y * 128;
  int wr = w >> 1, wc = w & 1;

  f32x4 acc[4][4] = {};

  for (int ks = 0; ks < 8; ++ks) {
    int k0 = ks * 32;
    __syncthreads();
#pragma unroll
    for (int t = 0; t < 4; ++t) {
      int bg = (t*4 + w) * 64;           // wave-uniform granule base
      int g = bg + lane;
      const unsigned short* src;
      if (bg < 512) {                    // A granules
        int r = g >> 2, kb = g & 3;
        src = A + (size_t)(bm + r) * 256 + k0 + kb*8;
      } else {                           // B granules
        int g2 = g - 512;
        int r = g2 >> 2, kb = g2 & 3;
        src = Bw + (size_t)(bn + r) * 256 + k0 + kb*8;
      }
      __builtin_amdgcn_global_load_lds(
        (const __attribute__((address_space(1))) unsigned int*)src,
        (__attribute__((address_space(3))) unsigned int*)&ABs[bg*8],
        16, 0, 0);
    }
    __syncthreads();

    bf16x8 af[4], bfr[4];
#pragma unroll
    for (int m = 0; m < 4; ++m)
      af[m] = *(const bf16x8*)&ABs[(wr*64 + m*16 + (lane&15))*32 + (lane>>4)*8];
#pragma unroll
    for (int n = 0; n < 4; ++n)
      bfr[n] = *(const bf16x8*)&ABs[4096 + (wc*64 + n*16 + (lane&15))*32 + (lane>>4)*8];
#pragma unroll
    for (int m = 0; m < 4; ++m)
#pragma unroll
      for (int n = 0; n < 4; ++n)
        acc[m][n] = __builtin_amdgcn_mfma_f32_16x16x32_bf16(af[m], bfr[n], acc[m][n], 0, 0, 0);
  }

  int rb = bm + wr*64 + (lane>>4)*4;
  int cb = bn + wc*64 + (lane&15);
#pragma unroll
  for (int m = 0; m < 4; ++m)
#pragma unroll
    for (int n = 0; n < 4; ++n)
#pragma unroll
      for (int i = 0; i < 4; ++i) {
        int row = rb + m*16 + i;
        int col = cb + n*16;
        float v = acc[m][n][i];
        if (OUT_BF16) {
          ((unsigned short*)Cv)[(size_t)row*ldc + col] = f2b(v);
        } else {
          ((float*)Cv)[(size_t)row*ldc + col] = v + R[(size_t)row*ldc + col];
        }
      }
}

// ---------------- per-point attention: one wave per point (bf16 QKV) ----------------
__global__ __launch_bounds__(256) void attn_kernel(const unsigned short* __restrict__ QKV,
                                                   const int* __restrict__ knn_idx,
                                                   unsigned short* __restrict__ attn_out,
                                                   float* __restrict__ xw_sum,
                                                   float* __restrict__ xw_cnt) {
  int p = blockIdx.x * 4 + (threadIdx.x >> 6);   // point id
  int lane = threadIdx.x & 63;
  size_t gbase = (size_t)(p >> 13) << 13;        // batch base
  size_t prow = (size_t)p * 768;

  ushort4 qv = *(const ushort4*)&QKV[prow + lane*4];
  ushort4 sv = *(const ushort4*)&QKV[prow + 512 + lane*4];
  float qx=b2f(qv.x), qy=b2f(qv.y), qz=b2f(qv.z), qw=b2f(qv.w);
  float sx=b2f(sv.x), sy=b2f(sv.y), sz=b2f(sv.z), sw=b2f(sv.w);

  int idx[KK];
#pragma unroll
  for (int j = 0; j < KK; ++j) idx[j] = knn_idx[p*KK + j];

  float s[KK];
  float vx[KK], vy[KK], vz[KK], vw[KK];
#pragma unroll
  for (int j = 0; j < KK; ++j) {
    size_t r = (gbase + idx[j]) * 768;
    ushort4 kv = *(const ushort4*)&QKV[r + 256 + lane*4];
    ushort4 vv = *(const ushort4*)&QKV[r + 512 + lane*4];
    float t = qx*b2f(kv.x) + qy*b2f(kv.y) + qz*b2f(kv.z) + qw*b2f(kv.w);
    t += __shfl_xor(t, 1);
    t += __shfl_xor(t, 2);
    t += __shfl_xor(t, 4);
    s[j] = t * 0.17677669529663687f;   // 1/sqrt(32)
    vx[j] = b2f(vv.x); vy[j] = b2f(vv.y); vz[j] = b2f(vv.z); vw[j] = b2f(vv.w);
  }

  float m = s[0];
#pragma unroll
  for (int j = 1; j < KK; ++j) m = fmaxf(m, s[j]);
  float e[KK], denom = 0.f;
#pragma unroll
  for (int j = 0; j < KK; ++j) { e[j] = expf(s[j] - m); denom += e[j]; }
  float inv = 1.0f / denom;
#pragma unroll
  for (int j = 0; j < KK; ++j) e[j] *= inv;

  float ox=0.f, oy=0.f, oz=0.f, ow=0.f;
#pragma unroll
  for (int j = 0; j < KK; ++j) {
    float a = e[j];
    ox += a * (vx[j] - sx);
    oy += a * (vy[j] - sy);
    oz += a * (vz[j] - sz);
    ow += a * (vw[j] - sw);
  }
  ushort4 ov;
  ov.x = f2b(ox); ov.y = f2b(oy); ov.z = f2b(oz); ov.w = f2b(ow);
  *(ushort4*)&attn_out[(size_t)p * 256 + lane*4] = ov;

  // x_w scatter: mean over heads (orbit of xor{8,16,32} = one lane per head)
#pragma unroll
  for (int j = 0; j < KK; ++j) {
    float t = e[j];
    t += __shfl_xor(t, 8);
    t += __shfl_xor(t, 16);
    t += __shfl_xor(t, 32);
    if (lane == 0) {
      atomicAdd(&xw_sum[gbase + idx[j]], t * 0.125f);
      atomicAdd(&xw_cnt[gbase + idx[j]], 1.0f);
    }
  }
}

// ---------------- finalize: xw_out = sum/(count+1) ----------------
__global__ void finalize_xw(const float* __restrict__ xw_sum,
                            const float* __restrict__ xw_cnt,
                            float* __restrict__ out) {
  int i = blockIdx.x * blockDim.x + threadIdx.x;
  if (i < NP) out[i] = xw_sum[i] / (xw_cnt[i] + 1.0f);
}

extern "C" void kernel_launch(void* const* d_in, const int* in_sizes, int n_in,
                              void* d_out, int out_size, void* d_ws, size_t ws_size,
                              hipStream_t stream) {
  const float* x     = (const float*)d_in[0];   // [B,V,E]
  const float* xv    = (const float*)d_in[1];   // [B,V,3]
  const float* w_in  = (const float*)d_in[2];   // [3E,E]
  const float* w_out = (const float*)d_in[3];   // [E,E]
  float* out = (float*)d_out;

  char* ws = (char*)d_ws;
  float4*         xv4    = (float4*)(ws + OFF_XV4);
  int*            knn    = (int*)(ws + OFF_KNN);
  float*          xw_sum = (float*)(ws + OFF_XWS);
  float*          xw_cnt = (float*)(ws + OFF_XWC);
  unsigned short* xb     = (unsigned short*)(ws + OFF_XB);
  unsigned short* wb     = (unsigned short*)(ws + OFF_WB);
  unsigned short* qkv    = (unsigned short*)(ws + OFF_QKV);
  unsigned short* ao     = (unsigned short*)(ws + OFF_AO);
  float4*         sxv4   = (float4*)(ws + OFF_SXV);
  int*            sperm  = (int*)(ws + OFF_SPM);

  prep_kernel<<<(NP + 255) / 256, 256, 0, stream>>>(xv, xv4, xw_sum, xw_cnt);
  cvt_bf16<<<(NP*256/4 + 255)/256, 256, 0, stream>>>(x, xb, NP*256/4);
  cvt_bf16<<<(768*256/4 + 255)/256, 256, 0, stream>>>(w_in, wb, 768*256/4);
  cvt_bf16<<<(256*256/4 + 255)/256, 256, 0, stream>>>(w_out, wb + 768*256, 256*256/4);

  sort_kernel<<<BB, 1024, 0, stream>>>(xv4, sxv4, sperm);
  knn_scan<<<NP/64, 256, 0, stream>>>(sxv4, sperm, knn);

  // QKV = x @ in_proj_w.T   [32768,768] bf16
  gemm_bf16<true><<<dim3(NP/128, 768/128), 256, 0, stream>>>(xb, wb, qkv, nullptr, 768);

  attn_kernel<<<NP / 4, 256, 0, stream>>>(qkv, knn, ao, xw_sum, xw_cnt);

  // x_out = attn_o @ out_proj_w.T + x   [32768,256] f32
  gemm_bf16<false><<<dim3(NP/128, 256/128), 256, 0, stream>>>(ao, wb + 768*256, out, x, 256);

  finalize_xw<<<NP / 256, 256, 0, stream>>>(xw_sum, xw_cnt, out + (size_t)NP * EE);
}

// Round 11
// 424.486 us; speedup vs baseline: 1.1267x; 1.1267x over previous
//
#include <hip/hip_runtime.h>
#include <hip/hip_bf16.h>
#include <math.h>

// Problem constants
#define BB 4
#define VV 8192
#define EE 256
#define HH 8
#define KK 6
#define NP (BB*VV)          // 32768 points total

// ---------------- workspace layout (bytes), total ~86.7 MB ----------------
#define OFF_XV4  0            // float4[NP]            524288
#define OFF_KNN  524288       // int[NP*6]             786432
#define OFF_XWS  1310720      // float[NP]             131072
#define OFF_XWC  1441792      // float[NP]             131072
#define OFF_XB   1572864      // bf16[NP*256]          16777216
#define OFF_WB   18350080     // bf16[1024*256]        524288
#define OFF_QKV  18874368     // bf16[NP*768]          50331648
#define OFF_AO   69206016     // bf16[NP*256]          16777216
#define OFF_SXV  85983232     // float4[NP] sorted     524288
#define OFF_SPM  86507520     // int[NP] perm          131072  -> ends 86638592

typedef float f32x4 __attribute__((ext_vector_type(4)));
typedef __bf16 bf16x8 __attribute__((ext_vector_type(8)));

__device__ __forceinline__ unsigned short f2b(float f) {
  __hip_bfloat16 h = __float2bfloat16(f);
  return *reinterpret_cast<unsigned short*>(&h);
}
__device__ __forceinline__ float b2f(unsigned short u) {
  unsigned v = ((unsigned)u) << 16;
  return __uint_as_float(v);
}

// monotone float -> uint map (total order)
__device__ __forceinline__ unsigned sortable(float f) {
  unsigned u = __float_as_uint(f);
  return u ^ ((unsigned)((int)u >> 31) | 0x80000000u);
}
__device__ __forceinline__ unsigned long long pack_key(float dist, int j) {
  return ((unsigned long long)sortable(dist) << 32) | (unsigned)j;
}
__device__ __forceinline__ float unpack_dist(unsigned long long k) {
  unsigned du = (unsigned)(k >> 32);
  du = (du & 0x80000000u) ? (du ^ 0x80000000u) : ~du;
  return __uint_as_float(du);
}

// key for an empty slot: dist=+INF, idx=0xFFFFFFFF
#define KINF 0xFF800000FFFFFFFFull

#define INSU(key) \
  if (key < k5) { \
    bool b4 = key < k4, b3 = key < k3, b2 = key < k2, b1 = key < k1, b0 = key < k0; \
    k5 = b4 ? k4 : key; \
    k4 = b4 ? (b3 ? k3 : key) : k4; \
    k3 = b3 ? (b2 ? k2 : key) : k3; \
    k2 = b2 ? (b1 ? k1 : key) : k2; \
    k1 = b1 ? (b0 ? k0 : key) : k1; \
    k0 = b0 ? key : k0; \
  }

// ---------------- prep: pack xyz+sq, zero scatter accumulators ----------------
__global__ void prep_kernel(const float* __restrict__ xv, float4* __restrict__ xv4,
                            float* __restrict__ xw_sum, float* __restrict__ xw_cnt) {
  int i = blockIdx.x * blockDim.x + threadIdx.x;
  if (i >= NP) return;
  float x0 = xv[i*3+0], x1 = xv[i*3+1], x2 = xv[i*3+2];
  // exact fp32 op order of the reference: ((x0*x0 + x1*x1) + x2*x2), no FMA contraction
  float sq = __fadd_rn(__fadd_rn(__fmul_rn(x0,x0), __fmul_rn(x1,x1)), __fmul_rn(x2,x2));
  xv4[i] = make_float4(x0, x1, x2, sq);
  xw_sum[i] = 0.f;
  xw_cnt[i] = 0.f;
}

// ---------------- f32 -> bf16 bulk convert (RNE) ----------------
__global__ void cvt_bf16(const float* __restrict__ src, unsigned short* __restrict__ dst, int n4) {
  int i = blockIdx.x * blockDim.x + threadIdx.x;
  if (i >= n4) return;
  float4 v = ((const float4*)src)[i];
  ushort4 o;
  o.x = f2b(v.x); o.y = f2b(v.y); o.z = f2b(v.z); o.w = f2b(v.w);
  ((ushort4*)dst)[i] = o;
}

// ---------------- per-batch bitonic sort by x (u64 keys in LDS) ----------------
// One block per batch, 1024 threads. key = sortable(x)<<32 | local_idx. (proven r7/r10)
__global__ __launch_bounds__(1024) void sort_kernel(const float4* __restrict__ xv4,
                                                    float4* __restrict__ sxv4,
                                                    int* __restrict__ sperm) {
  __shared__ unsigned long long keys[VV];   // 64 KB
  int tid = threadIdx.x;
  int bb = blockIdx.x * VV;
#pragma unroll
  for (int t = 0; t < 8; ++t) {
    int i = tid + t*1024;
    keys[i] = ((unsigned long long)sortable(xv4[bb + i].x) << 32) | (unsigned)i;
  }
  for (int k = 2; k <= VV; k <<= 1) {
    for (int jj = k >> 1; jj > 0; jj >>= 1) {
      __syncthreads();
#pragma unroll
      for (int t = 0; t < 4; ++t) {
        int c = tid + t*1024;                           // comparator 0..4095
        int i = ((c & ~(jj-1)) << 1) | (c & (jj-1));
        int p = i + jj;
        bool up = ((i & k) == 0);
        unsigned long long a = keys[i], b = keys[p];
        if ((a > b) == up) { keys[i] = b; keys[p] = a; }
      }
    }
  }
  __syncthreads();
#pragma unroll
  for (int t = 0; t < 8; ++t) {
    int r = tid + t*1024;
    int idx = (int)(unsigned)keys[r];    // batch-LOCAL original index
    sxv4[bb + r] = xv4[bb + idx];
    sperm[bb + r] = idx;
  }
}

// ---------------- KNN band scan over sorted-x (broadcast structure) ----------------
// Block = 4 waves; the block owns 64 CONSECUTIVE sorted queries (one per lane,
// shared across all 4 waves). Candidate chunks of 64 consecutive sorted
// positions walk outward from the block: waves 0,2 take the left side
// (offsets 0,-2,-4,... / -1,-3,...), waves 1,3 the right (+1,+3,... / +2,+4,...).
// Lane l preloads candidate l; all lanes process all 64 via readlane broadcast.
// Stop check once per chunk: next chunk's near-edge dx^2 > d5+MARGIN for all
// lanes (ballot). Exact selection: reference-order fp32 distance + u64
// (sortable dist, original idx) keys everywhere. Chunk 0 contains self (dist
// computes to exactly 0 since dot==sq elementwise with identical op order).
#define MARGIN 1e-3f

__global__ __launch_bounds__(256) void knn_band(const float4* __restrict__ sxv4,
                                                const int* __restrict__ sperm,
                                                int* __restrict__ knn_idx) {
  __shared__ unsigned long long sk[64][25];   // 4 waves x 6 keys (+pad)
  int lane = threadIdx.x & 63;
  int w = threadIdx.x >> 6;                   // wave 0..3
  int gblk = blockIdx.x * 64;                 // block's first sorted position
  int bb = (gblk >> 13) << 13;                // batch base (8192 % 64 == 0)
  int g = gblk + lane;

  float4 me = sxv4[g];
  float mx = me.x, my = me.y, mz = me.z, sqq = me.w;
  int myidx = sperm[g];                       // batch-LOCAL original index

  unsigned long long k0=KINF,k1=KINF,k2=KINF,k3=KINF,k4=KINF,k5=KINF;
  float d5f = INFINITY;

  // wave chunk schedule
  int cs, stepcs;
  bool leftside = (w == 0) || (w == 2);
  if (w == 0)      { cs = gblk;        stepcs = -128; }  // offsets 0,-2,-4,...
  else if (w == 2) { cs = gblk - 64;   stepcs = -128; }  // offsets -1,-3,...
  else if (w == 1) { cs = gblk + 64;   stepcs = +128; }  // offsets +1,+3,...
  else             { cs = gblk + 128;  stepcs = +128; }  // offsets +2,+4,...

  for (int itc = 0; itc < 129; ++itc) {
    if (cs < bb || cs + 64 > bb + VV) break;            // chunk OOB -> side done
    float4 cl = sxv4[cs + lane];                        // lane's candidate (coalesced)
    int    cj = sperm[cs + lane];
#pragma unroll 8
    for (int t = 0; t < 64; ++t) {
      float cx = __shfl(cl.x, t);
      float cy = __shfl(cl.y, t);
      float cz = __shfl(cl.z, t);
      float cw = __shfl(cl.w, t);
      int   jj = __shfl(cj, t);
      // reference fp32 semantics: d = (sq_v + sq_w) - 2*((xx+yy)+zz)
      float dot  = __fadd_rn(__fadd_rn(__fmul_rn(mx,cx), __fmul_rn(my,cy)), __fmul_rn(mz,cz));
      float dist = __fsub_rn(__fadd_rn(sqq, cw), __fmul_rn(2.0f, dot));
      if (dist <= d5f) {
        unsigned long long key = pack_key(dist, jj);
        if (key < k5) {
          bool b4 = key < k4, b3 = key < k3, b2 = key < k2, b1 = key < k1, b0 = key < k0;
          k5 = b4 ? k4 : key;
          k4 = b4 ? (b3 ? k3 : key) : k4;
          k3 = b3 ? (b2 ? k2 : key) : k3;
          k2 = b2 ? (b1 ? k1 : key) : k2;
          k1 = b1 ? (b0 ? k0 : key) : k1;
          k0 = b0 ? key : k0;
          d5f = unpack_dist(k5);
        }
      }
    }
    int ncs = cs + stepcs;
    if (ncs < bb || ncs + 64 > bb + VV) break;          // next OOB -> side done
    // near edge of next chunk: right side -> its first (lowest x); left -> its last
    float ex = leftside ? sxv4[ncs + 63].x : sxv4[ncs].x;
    float dxe = __fsub_rn(mx, ex);
    bool far = __fmul_rn(dxe, dxe) > (d5f + MARGIN);    // per-lane; conservative
    cs = ncs;
    if (__ballot(!far) == 0ull) break;                  // all lanes beyond window
  }

  sk[lane][w*6+0]=k0; sk[lane][w*6+1]=k1; sk[lane][w*6+2]=k2;
  sk[lane][w*6+3]=k3; sk[lane][w*6+4]=k4; sk[lane][w*6+5]=k5;
  __syncthreads();
  if (w == 0) {
#pragma unroll
    for (int s = 6; s < 24; ++s) {
      unsigned long long key = sk[lane][s];
      INSU(key);
    }
    int grow = bb + myidx;    // GLOBAL point id
    knn_idx[grow*6+0] = (int)(unsigned)k0;
    knn_idx[grow*6+1] = (int)(unsigned)k1;
    knn_idx[grow*6+2] = (int)(unsigned)k2;
    knn_idx[grow*6+3] = (int)(unsigned)k3;
    knn_idx[grow*6+4] = (int)(unsigned)k4;
    knn_idx[grow*6+5] = (int)(unsigned)k5;
  }
}

// ---------------- bf16 MFMA GEMM: C[m,n] = sum_k A[m,k]*B[n,k], K=256 ----------------
template<bool OUT_BF16>
__global__ __launch_bounds__(256) void gemm_bf16(const unsigned short* __restrict__ A,
                                                 const unsigned short* __restrict__ Bw,
                                                 void* __restrict__ Cv,
                                                 const float* __restrict__ R,
                                                 int ldc) {
  __shared__ unsigned short ABs[8192];   // A tile [0,4096), B tile [4096,8192) ushort units
  int tid = threadIdx.x;
  int lane = tid & 63;
  int w = tid >> 6;
  int bm = blockIdx.x * 128;
  int bn = blockIdx.y * 128;
  int wr = w >> 1, wc = w & 1;

  f32x4 acc[4][4] = {};

  for (int ks = 0; ks < 8; ++ks) {
    int k0 = ks * 32;
    __syncthreads();
#pragma unroll
    for (int t = 0; t < 4; ++t) {
      int bg = (t*4 + w) * 64;           // wave-uniform granule base
      int g = bg + lane;
      const unsigned short* src;
      if (bg < 512) {                    // A granules
        int r = g >> 2, kb = g & 3;
        src = A + (size_t)(bm + r) * 256 + k0 + kb*8;
      } else {                           // B granules
        int g2 = g - 512;
        int r = g2 >> 2, kb = g2 & 3;
        src = Bw + (size_t)(bn + r) * 256 + k0 + kb*8;
      }
      __builtin_amdgcn_global_load_lds(
        (const __attribute__((address_space(1))) unsigned int*)src,
        (__attribute__((address_space(3))) unsigned int*)&ABs[bg*8],
        16, 0, 0);
    }
    __syncthreads();

    bf16x8 af[4], bfr[4];
#pragma unroll
    for (int m = 0; m < 4; ++m)
      af[m] = *(const bf16x8*)&ABs[(wr*64 + m*16 + (lane&15))*32 + (lane>>4)*8];
#pragma unroll
    for (int n = 0; n < 4; ++n)
      bfr[n] = *(const bf16x8*)&ABs[4096 + (wc*64 + n*16 + (lane&15))*32 + (lane>>4)*8];
#pragma unroll
    for (int m = 0; m < 4; ++m)
#pragma unroll
      for (int n = 0; n < 4; ++n)
        acc[m][n] = __builtin_amdgcn_mfma_f32_16x16x32_bf16(af[m], bfr[n], acc[m][n], 0, 0, 0);
  }

  int rb = bm + wr*64 + (lane>>4)*4;
  int cb = bn + wc*64 + (lane&15);
#pragma unroll
  for (int m = 0; m < 4; ++m)
#pragma unroll
    for (int n = 0; n < 4; ++n)
#pragma unroll
      for (int i = 0; i < 4; ++i) {
        int row = rb + m*16 + i;
        int col = cb + n*16;
        float v = acc[m][n][i];
        if (OUT_BF16) {
          ((unsigned short*)Cv)[(size_t)row*ldc + col] = f2b(v);
        } else {
          ((float*)Cv)[(size_t)row*ldc + col] = v + R[(size_t)row*ldc + col];
        }
      }
}

// ---------------- per-point attention: one wave per point (bf16 QKV) ----------------
__global__ __launch_bounds__(256) void attn_kernel(const unsigned short* __restrict__ QKV,
                                                   const int* __restrict__ knn_idx,
                                                   unsigned short* __restrict__ attn_out,
                                                   float* __restrict__ xw_sum,
                                                   float* __restrict__ xw_cnt) {
  int p = blockIdx.x * 4 + (threadIdx.x >> 6);   // point id
  int lane = threadIdx.x & 63;
  size_t gbase = (size_t)(p >> 13) << 13;        // batch base
  size_t prow = (size_t)p * 768;

  ushort4 qv = *(const ushort4*)&QKV[prow + lane*4];
  ushort4 sv = *(const ushort4*)&QKV[prow + 512 + lane*4];
  float qx=b2f(qv.x), qy=b2f(qv.y), qz=b2f(qv.z), qw=b2f(qv.w);
  float sx=b2f(sv.x), sy=b2f(sv.y), sz=b2f(sv.z), sw=b2f(sv.w);

  int idx[KK];
#pragma unroll
  for (int j = 0; j < KK; ++j) idx[j] = knn_idx[p*KK + j];

  float s[KK];
  float vx[KK], vy[KK], vz[KK], vw[KK];
#pragma unroll
  for (int j = 0; j < KK; ++j) {
    size_t r = (gbase + idx[j]) * 768;
    ushort4 kv = *(const ushort4*)&QKV[r + 256 + lane*4];
    ushort4 vv = *(const ushort4*)&QKV[r + 512 + lane*4];
    float t = qx*b2f(kv.x) + qy*b2f(kv.y) + qz*b2f(kv.z) + qw*b2f(kv.w);
    t += __shfl_xor(t, 1);
    t += __shfl_xor(t, 2);
    t += __shfl_xor(t, 4);
    s[j] = t * 0.17677669529663687f;   // 1/sqrt(32)
    vx[j] = b2f(vv.x); vy[j] = b2f(vv.y); vz[j] = b2f(vv.z); vw[j] = b2f(vv.w);
  }

  float m = s[0];
#pragma unroll
  for (int j = 1; j < KK; ++j) m = fmaxf(m, s[j]);
  float e[KK], denom = 0.f;
#pragma unroll
  for (int j = 0; j < KK; ++j) { e[j] = expf(s[j] - m); denom += e[j]; }
  float inv = 1.0f / denom;
#pragma unroll
  for (int j = 0; j < KK; ++j) e[j] *= inv;

  float ox=0.f, oy=0.f, oz=0.f, ow=0.f;
#pragma unroll
  for (int j = 0; j < KK; ++j) {
    float a = e[j];
    ox += a * (vx[j] - sx);
    oy += a * (vy[j] - sy);
    oz += a * (vz[j] - sz);
    ow += a * (vw[j] - sw);
  }
  ushort4 ov;
  ov.x = f2b(ox); ov.y = f2b(oy); ov.z = f2b(oz); ov.w = f2b(ow);
  *(ushort4*)&attn_out[(size_t)p * 256 + lane*4] = ov;

  // x_w scatter: mean over heads (orbit of xor{8,16,32} = one lane per head)
#pragma unroll
  for (int j = 0; j < KK; ++j) {
    float t = e[j];
    t += __shfl_xor(t, 8);
    t += __shfl_xor(t, 16);
    t += __shfl_xor(t, 32);
    if (lane == 0) {
      atomicAdd(&xw_sum[gbase + idx[j]], t * 0.125f);
      atomicAdd(&xw_cnt[gbase + idx[j]], 1.0f);
    }
  }
}

// ---------------- finalize: xw_out = sum/(count+1) ----------------
__global__ void finalize_xw(const float* __restrict__ xw_sum,
                            const float* __restrict__ xw_cnt,
                            float* __restrict__ out) {
  int i = blockIdx.x * blockDim.x + threadIdx.x;
  if (i < NP) out[i] = xw_sum[i] / (xw_cnt[i] + 1.0f);
}

extern "C" void kernel_launch(void* const* d_in, const int* in_sizes, int n_in,
                              void* d_out, int out_size, void* d_ws, size_t ws_size,
                              hipStream_t stream) {
  const float* x     = (const float*)d_in[0];   // [B,V,E]
  const float* xv    = (const float*)d_in[1];   // [B,V,3]
  const float* w_in  = (const float*)d_in[2];   // [3E,E]
  const float* w_out = (const float*)d_in[3];   // [E,E]
  float* out = (float*)d_out;

  char* ws = (char*)d_ws;
  float4*         xv4    = (float4*)(ws + OFF_XV4);
  int*            knn    = (int*)(ws + OFF_KNN);
  float*          xw_sum = (float*)(ws + OFF_XWS);
  float*          xw_cnt = (float*)(ws + OFF_XWC);
  unsigned short* xb     = (unsigned short*)(ws + OFF_XB);
  unsigned short* wb     = (unsigned short*)(ws + OFF_WB);
  unsigned short* qkv    = (unsigned short*)(ws + OFF_QKV);
  unsigned short* ao     = (unsigned short*)(ws + OFF_AO);
  float4*         sxv4   = (float4*)(ws + OFF_SXV);
  int*            sperm  = (int*)(ws + OFF_SPM);

  prep_kernel<<<(NP + 255) / 256, 256, 0, stream>>>(xv, xv4, xw_sum, xw_cnt);
  cvt_bf16<<<(NP*256/4 + 255)/256, 256, 0, stream>>>(x, xb, NP*256/4);
  cvt_bf16<<<(768*256/4 + 255)/256, 256, 0, stream>>>(w_in, wb, 768*256/4);
  cvt_bf16<<<(256*256/4 + 255)/256, 256, 0, stream>>>(w_out, wb + 768*256, 256*256/4);

  sort_kernel<<<BB, 1024, 0, stream>>>(xv4, sxv4, sperm);
  knn_band<<<NP/64, 256, 0, stream>>>(sxv4, sperm, knn);

  // QKV = x @ in_proj_w.T   [32768,768] bf16
  gemm_bf16<true><<<dim3(NP/128, 768/128), 256, 0, stream>>>(xb, wb, qkv, nullptr, 768);

  attn_kernel<<<NP / 4, 256, 0, stream>>>(qkv, knn, ao, xw_sum, xw_cnt);

  // x_out = attn_o @ out_proj_w.T + x   [32768,256] f32
  gemm_bf16<false><<<dim3(NP/128, 256/128), 256, 0, stream>>>(ao, wb + 768*256, out, x, 256);

  finalize_xw<<<NP / 256, 256, 0, stream>>>(xw_sum, xw_cnt, out + (size_t)NP * EE);
}

// Round 12
// 370.973 us; speedup vs baseline: 1.2893x; 1.1443x over previous
//
#include <hip/hip_runtime.h>
#include <hip/hip_bf16.h>
#include <math.h>

// Problem constants
#define BB 4
#define VV 8192
#define EE 256
#define HH 8
#define KK 6
#define NP (BB*VV)          // 32768 points total

// ---------------- workspace layout (bytes), total ~86.7 MB ----------------
#define OFF_XV4  0            // float4[NP]            524288
#define OFF_KNN  524288       // int[NP*6]             786432
#define OFF_XWS  1310720      // float[NP]             131072
#define OFF_XWC  1441792      // float[NP]             131072
#define OFF_XB   1572864      // bf16[NP*256]          16777216
#define OFF_WB   18350080     // bf16[1024*256]        524288
#define OFF_QKV  18874368     // bf16[NP*768]          50331648
#define OFF_AO   69206016     // bf16[NP*256]          16777216
#define OFF_SXV  85983232     // float4[NP] sorted     524288
#define OFF_SPM  86507520     // int[NP] perm          131072  -> ends 86638592

typedef float f32x4 __attribute__((ext_vector_type(4)));
typedef __bf16 bf16x8 __attribute__((ext_vector_type(8)));

__device__ __forceinline__ unsigned short f2b(float f) {
  __hip_bfloat16 h = __float2bfloat16(f);
  return *reinterpret_cast<unsigned short*>(&h);
}
__device__ __forceinline__ float b2f(unsigned short u) {
  unsigned v = ((unsigned)u) << 16;
  return __uint_as_float(v);
}

// monotone float -> uint map (total order)
__device__ __forceinline__ unsigned sortable(float f) {
  unsigned u = __float_as_uint(f);
  return u ^ ((unsigned)((int)u >> 31) | 0x80000000u);
}
__device__ __forceinline__ unsigned long long pack_key(float dist, int j) {
  return ((unsigned long long)sortable(dist) << 32) | (unsigned)j;
}
__device__ __forceinline__ float unpack_dist(unsigned long long k) {
  unsigned du = (unsigned)(k >> 32);
  du = (du & 0x80000000u) ? (du ^ 0x80000000u) : ~du;
  return __uint_as_float(du);
}

// key for an empty slot: dist=+INF, idx=0xFFFFFFFF
#define KINF 0xFF800000FFFFFFFFull

#define INSU(key) \
  if (key < k5) { \
    bool b4 = key < k4, b3 = key < k3, b2 = key < k2, b1 = key < k1, b0 = key < k0; \
    k5 = b4 ? k4 : key; \
    k4 = b4 ? (b3 ? k3 : key) : k4; \
    k3 = b3 ? (b2 ? k2 : key) : k3; \
    k2 = b2 ? (b1 ? k1 : key) : k2; \
    k1 = b1 ? (b0 ? k0 : key) : k1; \
    k0 = b0 ? key : k0; \
  }

// ---------------- prep: pack xyz+sq, zero scatter accumulators ----------------
__global__ void prep_kernel(const float* __restrict__ xv, float4* __restrict__ xv4,
                            float* __restrict__ xw_sum, float* __restrict__ xw_cnt) {
  int i = blockIdx.x * blockDim.x + threadIdx.x;
  if (i >= NP) return;
  float x0 = xv[i*3+0], x1 = xv[i*3+1], x2 = xv[i*3+2];
  // exact fp32 op order of the reference: ((x0*x0 + x1*x1) + x2*x2), no FMA contraction
  float sq = __fadd_rn(__fadd_rn(__fmul_rn(x0,x0), __fmul_rn(x1,x1)), __fmul_rn(x2,x2));
  xv4[i] = make_float4(x0, x1, x2, sq);
  xw_sum[i] = 0.f;
  xw_cnt[i] = 0.f;
}

// ---------------- f32 -> bf16 bulk convert (RNE) ----------------
__global__ void cvt_bf16(const float* __restrict__ src, unsigned short* __restrict__ dst, int n4) {
  int i = blockIdx.x * blockDim.x + threadIdx.x;
  if (i >= n4) return;
  float4 v = ((const float4*)src)[i];
  ushort4 o;
  o.x = f2b(v.x); o.y = f2b(v.y); o.z = f2b(v.z); o.w = f2b(v.w);
  ((ushort4*)dst)[i] = o;
}

// ---------------- per-batch bitonic sort by x (u64 keys in LDS) ----------------
// One block per batch, 1024 threads. key = sortable(x)<<32 | local_idx. (proven r7/r10)
__global__ __launch_bounds__(1024) void sort_kernel(const float4* __restrict__ xv4,
                                                    float4* __restrict__ sxv4,
                                                    int* __restrict__ sperm) {
  __shared__ unsigned long long keys[VV];   // 64 KB
  int tid = threadIdx.x;
  int bb = blockIdx.x * VV;
#pragma unroll
  for (int t = 0; t < 8; ++t) {
    int i = tid + t*1024;
    keys[i] = ((unsigned long long)sortable(xv4[bb + i].x) << 32) | (unsigned)i;
  }
  for (int k = 2; k <= VV; k <<= 1) {
    for (int jj = k >> 1; jj > 0; jj >>= 1) {
      __syncthreads();
#pragma unroll
      for (int t = 0; t < 4; ++t) {
        int c = tid + t*1024;                           // comparator 0..4095
        int i = ((c & ~(jj-1)) << 1) | (c & (jj-1));
        int p = i + jj;
        bool up = ((i & k) == 0);
        unsigned long long a = keys[i], b = keys[p];
        if ((a > b) == up) { keys[i] = b; keys[p] = a; }
      }
    }
  }
  __syncthreads();
#pragma unroll
  for (int t = 0; t < 8; ++t) {
    int r = tid + t*1024;
    int idx = (int)(unsigned)keys[r];    // batch-LOCAL original index
    sxv4[bb + r] = xv4[bb + idx];
    sperm[bb + r] = idx;
  }
}

// ---------------- KNN band scan over sorted-x (r4 broadcast structure) ----------------
// Block = 64 consecutive sorted queries (one per lane, shared by all 4 waves).
// Candidate tiles = 64 consecutive sorted positions, walking outward from the
// band. Wave w owns right tiles r%4==w (r=0 is the band itself) and left tiles
// (l-1)%4==w (l>=1). Per tile: coalesced load -> wave-private LDS stage (same-
// wave DS ops are in-order; no barrier needed), then 64 candidates, each one
// wave-uniform ds_read_b128 (free broadcast) + ~9 VALU. Early-out per SIDE per
// wave: the processed tile's far-edge x bounds all future tiles' dx (sorted =>
// monotone); stop when dx_far^2 > d5+MARGIN for ALL lanes (one ballot/tile).
// Conservative: wave's partial d5 >= true d5; MARGIN=1e-3 >> 1e-5 fp32 rounding
// of the reference-order distance. Exact tie-break via u64 (sortable dist, idx)
// keys (order-independent). Self lands in the band tile with dist exactly 0.
#define MARGIN 1e-3f

__global__ __launch_bounds__(256) void knn_band(const float4* __restrict__ sxv4,
                                                const int* __restrict__ sperm,
                                                int* __restrict__ knn_idx) {
  __shared__ float4 stile[4][64];             // 4 KB  (per-wave tile)
  __shared__ int    sidx[4][64];              // 1 KB  (per-wave idx)
  __shared__ unsigned long long sk[64][25];   // 12.5 KB (merge)
  int lane = threadIdx.x & 63;
  int w = threadIdx.x >> 6;                   // wave 0..3
  int gblk = blockIdx.x * 64;                 // block's first sorted position
  int bb = (gblk >> 13) << 13;                // batch base (8192 % 64 == 0)
  int bbend = bb + VV;
  int g = gblk + lane;

  float4 me = sxv4[g];
  float mx = me.x, my = me.y, mz = me.z, sqq = me.w;
  int myidx = sperm[g];                       // batch-LOCAL original index

  unsigned long long k0=KINF,k1=KINF,k2=KINF,k3=KINF,k4=KINF,k5=KINF;
  float d5f = INFINITY;

  int rt = w;          // right tile counter (tile start = gblk + rt*64)
  int lt = w + 1;      // left tile counter  (tile start = gblk - lt*64)
  bool rdone = false, ldone = false;

  for (int guard = 0; guard < 260 && (!rdone || !ldone); ++guard) {
    // ---- right side tile ----
    if (!rdone) {
      int start = gblk + rt * 64;
      if (start >= bbend) { rdone = true; }
      else {
        float4 c = sxv4[start + lane];
        int jj = sperm[start + lane];
        stile[w][lane] = c;
        sidx[w][lane] = jj;
        __builtin_amdgcn_wave_barrier();      // keep ds_write before ds_read
#pragma unroll 8
        for (int t = 0; t < 64; ++t) {
          float4 p = stile[w][t];             // wave-uniform -> broadcast
          float dot  = __fadd_rn(__fadd_rn(__fmul_rn(mx,p.x), __fmul_rn(my,p.y)), __fmul_rn(mz,p.z));
          float dist = __fsub_rn(__fadd_rn(sqq, p.w), __fmul_rn(2.0f, dot));
          if (dist <= d5f) {
            unsigned long long key = pack_key(dist, sidx[w][t]);
            INSU(key);
            d5f = unpack_dist(k5);
          }
        }
        rt += 4;
        if (gblk + rt * 64 >= bbend) { rdone = true; }
        else {
          float fx = stile[w][63].x;          // far edge of processed tile
          float dxe = __fsub_rn(fx, mx);
          bool near = __fmul_rn(dxe, dxe) <= __fadd_rn(d5f, MARGIN);
          rdone = (__ballot(near) == 0ull);
        }
      }
    }
    // ---- left side tile ----
    if (!ldone) {
      int start = gblk - lt * 64;
      if (start < bb) { ldone = true; }
      else {
        float4 c = sxv4[start + lane];
        int jj = sperm[start + lane];
        stile[w][lane] = c;
        sidx[w][lane] = jj;
        __builtin_amdgcn_wave_barrier();
#pragma unroll 8
        for (int t = 0; t < 64; ++t) {
          float4 p = stile[w][t];
          float dot  = __fadd_rn(__fadd_rn(__fmul_rn(mx,p.x), __fmul_rn(my,p.y)), __fmul_rn(mz,p.z));
          float dist = __fsub_rn(__fadd_rn(sqq, p.w), __fmul_rn(2.0f, dot));
          if (dist <= d5f) {
            unsigned long long key = pack_key(dist, sidx[w][t]);
            INSU(key);
            d5f = unpack_dist(k5);
          }
        }
        lt += 4;
        if (gblk - lt * 64 < bb) { ldone = true; }
        else {
          float fx = stile[w][0].x;           // far edge (lowest x) of processed tile
          float dxe = __fsub_rn(mx, fx);
          bool near = __fmul_rn(dxe, dxe) <= __fadd_rn(d5f, MARGIN);
          ldone = (__ballot(near) == 0ull);
        }
      }
    }
  }

  sk[lane][w*6+0]=k0; sk[lane][w*6+1]=k1; sk[lane][w*6+2]=k2;
  sk[lane][w*6+3]=k3; sk[lane][w*6+4]=k4; sk[lane][w*6+5]=k5;
  __syncthreads();
  if (w == 0) {
#pragma unroll
    for (int s = 6; s < 24; ++s) {
      unsigned long long key = sk[lane][s];
      INSU(key);
    }
    int grow = bb + myidx;    // GLOBAL point id
    knn_idx[grow*6+0] = (int)(unsigned)k0;
    knn_idx[grow*6+1] = (int)(unsigned)k1;
    knn_idx[grow*6+2] = (int)(unsigned)k2;
    knn_idx[grow*6+3] = (int)(unsigned)k3;
    knn_idx[grow*6+4] = (int)(unsigned)k4;
    knn_idx[grow*6+5] = (int)(unsigned)k5;
  }
}

// ---------------- bf16 MFMA GEMM: C[m,n] = sum_k A[m,k]*B[n,k], K=256 ----------------
template<bool OUT_BF16>
__global__ __launch_bounds__(256) void gemm_bf16(const unsigned short* __restrict__ A,
                                                 const unsigned short* __restrict__ Bw,
                                                 void* __restrict__ Cv,
                                                 const float* __restrict__ R,
                                                 int ldc) {
  __shared__ unsigned short ABs[8192];   // A tile [0,4096), B tile [4096,8192) ushort units
  int tid = threadIdx.x;
  int lane = tid & 63;
  int w = tid >> 6;
  int bm = blockIdx.x * 128;
  int bn = blockIdx.y * 128;
  int wr = w >> 1, wc = w & 1;

  f32x4 acc[4][4] = {};

  for (int ks = 0; ks < 8; ++ks) {
    int k0 = ks * 32;
    __syncthreads();
#pragma unroll
    for (int t = 0; t < 4; ++t) {
      int bg = (t*4 + w) * 64;           // wave-uniform granule base
      int g = bg + lane;
      const unsigned short* src;
      if (bg < 512) {                    // A granules
        int r = g >> 2, kb = g & 3;
        src = A + (size_t)(bm + r) * 256 + k0 + kb*8;
      } else {                           // B granules
        int g2 = g - 512;
        int r = g2 >> 2, kb = g2 & 3;
        src = Bw + (size_t)(bn + r) * 256 + k0 + kb*8;
      }
      __builtin_amdgcn_global_load_lds(
        (const __attribute__((address_space(1))) unsigned int*)src,
        (__attribute__((address_space(3))) unsigned int*)&ABs[bg*8],
        16, 0, 0);
    }
    __syncthreads();

    bf16x8 af[4], bfr[4];
#pragma unroll
    for (int m = 0; m < 4; ++m)
      af[m] = *(const bf16x8*)&ABs[(wr*64 + m*16 + (lane&15))*32 + (lane>>4)*8];
#pragma unroll
    for (int n = 0; n < 4; ++n)
      bfr[n] = *(const bf16x8*)&ABs[4096 + (wc*64 + n*16 + (lane&15))*32 + (lane>>4)*8];
#pragma unroll
    for (int m = 0; m < 4; ++m)
#pragma unroll
      for (int n = 0; n < 4; ++n)
        acc[m][n] = __builtin_amdgcn_mfma_f32_16x16x32_bf16(af[m], bfr[n], acc[m][n], 0, 0, 0);
  }

  int rb = bm + wr*64 + (lane>>4)*4;
  int cb = bn + wc*64 + (lane&15);
#pragma unroll
  for (int m = 0; m < 4; ++m)
#pragma unroll
    for (int n = 0; n < 4; ++n)
#pragma unroll
      for (int i = 0; i < 4; ++i) {
        int row = rb + m*16 + i;
        int col = cb + n*16;
        float v = acc[m][n][i];
        if (OUT_BF16) {
          ((unsigned short*)Cv)[(size_t)row*ldc + col] = f2b(v);
        } else {
          ((float*)Cv)[(size_t)row*ldc + col] = v + R[(size_t)row*ldc + col];
        }
      }
}

// ---------------- per-point attention: one wave per point (bf16 QKV) ----------------
__global__ __launch_bounds__(256) void attn_kernel(const unsigned short* __restrict__ QKV,
                                                   const int* __restrict__ knn_idx,
                                                   unsigned short* __restrict__ attn_out,
                                                   float* __restrict__ xw_sum,
                                                   float* __restrict__ xw_cnt) {
  int p = blockIdx.x * 4 + (threadIdx.x >> 6);   // point id
  int lane = threadIdx.x & 63;
  size_t gbase = (size_t)(p >> 13) << 13;        // batch base
  size_t prow = (size_t)p * 768;

  ushort4 qv = *(const ushort4*)&QKV[prow + lane*4];
  ushort4 sv = *(const ushort4*)&QKV[prow + 512 + lane*4];
  float qx=b2f(qv.x), qy=b2f(qv.y), qz=b2f(qv.z), qw=b2f(qv.w);
  float sx=b2f(sv.x), sy=b2f(sv.y), sz=b2f(sv.z), sw=b2f(sv.w);

  int idx[KK];
#pragma unroll
  for (int j = 0; j < KK; ++j) idx[j] = knn_idx[p*KK + j];

  float s[KK];
  float vx[KK], vy[KK], vz[KK], vw[KK];
#pragma unroll
  for (int j = 0; j < KK; ++j) {
    size_t r = (gbase + idx[j]) * 768;
    ushort4 kv = *(const ushort4*)&QKV[r + 256 + lane*4];
    ushort4 vv = *(const ushort4*)&QKV[r + 512 + lane*4];
    float t = qx*b2f(kv.x) + qy*b2f(kv.y) + qz*b2f(kv.z) + qw*b2f(kv.w);
    t += __shfl_xor(t, 1);
    t += __shfl_xor(t, 2);
    t += __shfl_xor(t, 4);
    s[j] = t * 0.17677669529663687f;   // 1/sqrt(32)
    vx[j] = b2f(vv.x); vy[j] = b2f(vv.y); vz[j] = b2f(vv.z); vw[j] = b2f(vv.w);
  }

  float m = s[0];
#pragma unroll
  for (int j = 1; j < KK; ++j) m = fmaxf(m, s[j]);
  float e[KK], denom = 0.f;
#pragma unroll
  for (int j = 0; j < KK; ++j) { e[j] = expf(s[j] - m); denom += e[j]; }
  float inv = 1.0f / denom;
#pragma unroll
  for (int j = 0; j < KK; ++j) e[j] *= inv;

  float ox=0.f, oy=0.f, oz=0.f, ow=0.f;
#pragma unroll
  for (int j = 0; j < KK; ++j) {
    float a = e[j];
    ox += a * (vx[j] - sx);
    oy += a * (vy[j] - sy);
    oz += a * (vz[j] - sz);
    ow += a * (vw[j] - sw);
  }
  ushort4 ov;
  ov.x = f2b(ox); ov.y = f2b(oy); ov.z = f2b(oz); ov.w = f2b(ow);
  *(ushort4*)&attn_out[(size_t)p * 256 + lane*4] = ov;

  // x_w scatter: mean over heads (orbit of xor{8,16,32} = one lane per head)
#pragma unroll
  for (int j = 0; j < KK; ++j) {
    float t = e[j];
    t += __shfl_xor(t, 8);
    t += __shfl_xor(t, 16);
    t += __shfl_xor(t, 32);
    if (lane == 0) {
      atomicAdd(&xw_sum[gbase + idx[j]], t * 0.125f);
      atomicAdd(&xw_cnt[gbase + idx[j]], 1.0f);
    }
  }
}

// ---------------- finalize: xw_out = sum/(count+1) ----------------
__global__ void finalize_xw(const float* __restrict__ xw_sum,
                            const float* __restrict__ xw_cnt,
                            float* __restrict__ out) {
  int i = blockIdx.x * blockDim.x + threadIdx.x;
  if (i < NP) out[i] = xw_sum[i] / (xw_cnt[i] + 1.0f);
}

extern "C" void kernel_launch(void* const* d_in, const int* in_sizes, int n_in,
                              void* d_out, int out_size, void* d_ws, size_t ws_size,
                              hipStream_t stream) {
  const float* x     = (const float*)d_in[0];   // [B,V,E]
  const float* xv    = (const float*)d_in[1];   // [B,V,3]
  const float* w_in  = (const float*)d_in[2];   // [3E,E]
  const float* w_out = (const float*)d_in[3];   // [E,E]
  float* out = (float*)d_out;

  char* ws = (char*)d_ws;
  float4*         xv4    = (float4*)(ws + OFF_XV4);
  int*            knn    = (int*)(ws + OFF_KNN);
  float*          xw_sum = (float*)(ws + OFF_XWS);
  float*          xw_cnt = (float*)(ws + OFF_XWC);
  unsigned short* xb     = (unsigned short*)(ws + OFF_XB);
  unsigned short* wb     = (unsigned short*)(ws + OFF_WB);
  unsigned short* qkv    = (unsigned short*)(ws + OFF_QKV);
  unsigned short* ao     = (unsigned short*)(ws + OFF_AO);
  float4*         sxv4   = (float4*)(ws + OFF_SXV);
  int*            sperm  = (int*)(ws + OFF_SPM);

  prep_kernel<<<(NP + 255) / 256, 256, 0, stream>>>(xv, xv4, xw_sum, xw_cnt);
  cvt_bf16<<<(NP*256/4 + 255)/256, 256, 0, stream>>>(x, xb, NP*256/4);
  cvt_bf16<<<(768*256/4 + 255)/256, 256, 0, stream>>>(w_in, wb, 768*256/4);
  cvt_bf16<<<(256*256/4 + 255)/256, 256, 0, stream>>>(w_out, wb + 768*256, 256*256/4);

  sort_kernel<<<BB, 1024, 0, stream>>>(xv4, sxv4, sperm);
  knn_band<<<NP/64, 256, 0, stream>>>(sxv4, sperm, knn);

  // QKV = x @ in_proj_w.T   [32768,768] bf16
  gemm_bf16<true><<<dim3(NP/128, 768/128), 256, 0, stream>>>(xb, wb, qkv, nullptr, 768);

  attn_kernel<<<NP / 4, 256, 0, stream>>>(qkv, knn, ao, xw_sum, xw_cnt);

  // x_out = attn_o @ out_proj_w.T + x   [32768,256] f32
  gemm_bf16<false><<<dim3(NP/128, 256/128), 256, 0, stream>>>(ao, wb + 768*256, out, x, 256);

  finalize_xw<<<NP / 256, 256, 0, stream>>>(xw_sum, xw_cnt, out + (size_t)NP * EE);
}